// Round 2
// baseline (494.022 us; speedup 1.0000x reference)
//
#include <hip/hip_runtime.h>

// Cosine similarity per row: q,d are [N, 256] fp32; out is [N] fp32.
// One 64-lane wave per 4 rows: lane i loads float4 at column 4*i for each of
// 4 consecutive rows from each of q,d (8 outstanding 16 B loads = 8 KiB/wave
// in flight), accumulates qq/dd/qd partials per row, width-64 butterfly
// reduction, lane 0 writes a single float4 (4 results). Memory-bound:
// 512 MiB in, 1 MiB out; floor ~85 us at 6.3 TB/s.
constexpr int ROWS_PER_WAVE = 4;

__global__ __launch_bounds__(256) void cosine_rows_kernel(
    const float4* __restrict__ q4,   // [N, 64] float4 view of [N,256] f32
    const float4* __restrict__ d4,
    float4* __restrict__ out4,       // [N/4] float4 view of [N] f32
    int n_rows)
{
    const int wave = (blockIdx.x * blockDim.x + threadIdx.x) >> 6;
    const int lane = threadIdx.x & 63;
    const int row0 = wave * ROWS_PER_WAVE;
    if (row0 >= n_rows) return;

    // Issue all 8 loads before any dependent math (MLP).
    float4 qv[ROWS_PER_WAVE], dv[ROWS_PER_WAVE];
    #pragma unroll
    for (int r = 0; r < ROWS_PER_WAVE; ++r) {
        const size_t base = (size_t)(row0 + r) * 64 + lane;
        qv[r] = q4[base];
        dv[r] = d4[base];
    }

    float res[ROWS_PER_WAVE];
    #pragma unroll
    for (int r = 0; r < ROWS_PER_WAVE; ++r) {
        float qq = qv[r].x * qv[r].x + qv[r].y * qv[r].y +
                   qv[r].z * qv[r].z + qv[r].w * qv[r].w;
        float dd = dv[r].x * dv[r].x + dv[r].y * dv[r].y +
                   dv[r].z * dv[r].z + dv[r].w * dv[r].w;
        float qd = qv[r].x * dv[r].x + qv[r].y * dv[r].y +
                   qv[r].z * dv[r].z + qv[r].w * dv[r].w;

        // Wave-64 butterfly (xor) reduction: every lane ends with full sums.
        #pragma unroll
        for (int off = 32; off > 0; off >>= 1) {
            qq += __shfl_xor(qq, off, 64);
            dd += __shfl_xor(dd, off, 64);
            qd += __shfl_xor(qd, off, 64);
        }
        res[r] = qd * rsqrtf(qq * dd);
    }

    if (lane == 0) {
        out4[wave] = make_float4(res[0], res[1], res[2], res[3]);
    }
}

extern "C" void kernel_launch(void* const* d_in, const int* in_sizes, int n_in,
                              void* d_out, int out_size, void* d_ws, size_t ws_size,
                              hipStream_t stream) {
    const float4* q4 = (const float4*)d_in[0];
    const float4* d4 = (const float4*)d_in[1];
    float4* out4 = (float4*)d_out;

    const int D = 256;
    const int n_rows = in_sizes[0] / D;   // 262144, divisible by 4

    // 256 threads = 4 waves/block; each wave does 4 rows -> 16 rows/block.
    const int rows_per_block = 4 * ROWS_PER_WAVE;
    const int grid = (n_rows + rows_per_block - 1) / rows_per_block;

    cosine_rows_kernel<<<grid, 256, 0, stream>>>(q4, d4, out4, n_rows);
}

// Round 4
// 470.851 us; speedup vs baseline: 1.0492x; 1.0492x over previous
//
#include <hip/hip_runtime.h>

// Cosine similarity per row: q,d are [N, 256] fp32; out is [N] fp32.
// One 64-lane wave per 2 rows: lane i loads the 16B vector at column 4*i of
// each row (1 KiB/row coalesced; 4 loads in flight/wave), accumulates
// qq/dd/qd per row, width-64 xor-butterfly reduction, lane 0 writes one
// float2. Inputs streamed exactly once -> nontemporal (nt) loads/stores.
// Memory-bound: 512 MiB in, 1 MiB out, floor ~85 us at 6.3 TB/s.
//
// Note: __builtin_nontemporal_load requires native clang vector types, not
// HIP_vector_type structs (R2 compile failure) -> use ext_vector_type.
typedef float fx4 __attribute__((ext_vector_type(4)));
typedef float fx2 __attribute__((ext_vector_type(2)));

constexpr int ROWS_PER_WAVE = 2;

__global__ __launch_bounds__(256) void cosine_rows_kernel(
    const fx4* __restrict__ q4,   // [N, 64] fx4 view of [N,256] f32
    const fx4* __restrict__ d4,
    fx2* __restrict__ out2,       // [N/2] fx2 view of [N] f32
    int n_rows)
{
    const int wave = (blockIdx.x * blockDim.x + threadIdx.x) >> 6;
    const int lane = threadIdx.x & 63;
    const int row0 = wave * ROWS_PER_WAVE;
    if (row0 >= n_rows) return;

    fx4 qv[ROWS_PER_WAVE], dv[ROWS_PER_WAVE];
    #pragma unroll
    for (int r = 0; r < ROWS_PER_WAVE; ++r) {
        const size_t base = (size_t)(row0 + r) * 64 + lane;
        qv[r] = __builtin_nontemporal_load(&q4[base]);
        dv[r] = __builtin_nontemporal_load(&d4[base]);
    }

    float res[ROWS_PER_WAVE];
    #pragma unroll
    for (int r = 0; r < ROWS_PER_WAVE; ++r) {
        float qq = qv[r].x * qv[r].x + qv[r].y * qv[r].y +
                   qv[r].z * qv[r].z + qv[r].w * qv[r].w;
        float dd = dv[r].x * dv[r].x + dv[r].y * dv[r].y +
                   dv[r].z * dv[r].z + dv[r].w * dv[r].w;
        float qd = qv[r].x * dv[r].x + qv[r].y * dv[r].y +
                   qv[r].z * dv[r].z + qv[r].w * dv[r].w;

        // Wave-64 xor butterfly: every lane ends with the full row sums.
        #pragma unroll
        for (int off = 32; off > 0; off >>= 1) {
            qq += __shfl_xor(qq, off, 64);
            dd += __shfl_xor(dd, off, 64);
            qd += __shfl_xor(qd, off, 64);
        }
        res[r] = qd * rsqrtf(qq * dd);
    }

    if (lane == 0) {
        fx2 o;
        o.x = res[0];
        o.y = res[1];
        __builtin_nontemporal_store(o, &out2[wave]);
    }
}

extern "C" void kernel_launch(void* const* d_in, const int* in_sizes, int n_in,
                              void* d_out, int out_size, void* d_ws, size_t ws_size,
                              hipStream_t stream) {
    const fx4* q4 = (const fx4*)d_in[0];
    const fx4* d4 = (const fx4*)d_in[1];
    fx2* out2 = (fx2*)d_out;

    const int D = 256;
    const int n_rows = in_sizes[0] / D;   // 262144, divisible by 2

    // 256 threads = 4 waves/block; each wave does 2 rows -> 8 rows/block.
    const int rows_per_block = 4 * ROWS_PER_WAVE;
    const int grid = (n_rows + rows_per_block - 1) / rows_per_block;

    cosine_rows_kernel<<<grid, 256, 0, stream>>>(q4, d4, out2, n_rows);
}